// Round 1
// baseline (363.015 us; speedup 1.0000x reference)
//
#include <hip/hip_runtime.h>

// Problem dims
#define NN 64      // nodes
#define EE 128     // edges
#define GG 4       // graphs
#define D0 9
#define EDIM 4
#define H1 2000
#define H2 500
#define H3 100
#define FF1 1000
#define FF2 100
#define FF3 50
#define KDIM 384   // 64 nodes * 6 channels (4 edge-attr + 1 bias + 1 root)

// Workspace layout (floats)
#define OFF_A    0          // 64*384        = 24576
#define OFF_PRE1 24576      // 64*2000       = 128000
#define OFF_PRE2 152576     // 64*500        = 32000
#define OFF_PRE3 184576     // 64*100        = 6400
#define OFF_N3   190976     // 384*100       = 38400
#define OFF_N1   229376     // 384*2000      = 768000   (aliased with N2P)
#define OFF_N2P  229376     // 8 * 384*500   = 1536000  (partials)
// total = 1,765,376 floats = 7.06 MB

// ---------------------------------------------------------------------------
// K0: build A-hat, fill bias-preloaded pre-act buffers, zero n3,
//     and do layer-1 GEMM1 (K=9, trivial) — all independent work fused.
// ---------------------------------------------------------------------------
__global__ __launch_bounds__(256) void k_init(
    const float* __restrict__ x, const int* __restrict__ edge_index,
    const float* __restrict__ edge_attr,
    const float* __restrict__ We1, const float* __restrict__ be1,
    const float* __restrict__ root1,
    const float* __restrict__ b1, const float* __restrict__ b2,
    const float* __restrict__ b3, float* __restrict__ ws)
{
    const int b = blockIdx.x, tid = threadIdx.x;
    if (b == 0) {
        // A-hat: zero, scatter edges, set identity (root) channel
        float* A = ws + OFF_A;
        for (int i = tid; i < NN * KDIM; i += 256) A[i] = 0.f;
        __syncthreads();
        if (tid < EE) {
            int s = edge_index[tid];
            int t = edge_index[EE + tid];
            float* row = A + t * KDIM + s * 6;
            #pragma unroll
            for (int d = 0; d < 4; ++d) atomicAdd(row + d, edge_attr[tid * 4 + d]);
            atomicAdd(row + 4, 1.0f);      // bias channel: edge count
        }
        if (tid < NN) A[tid * KDIM + tid * 6 + 5] = 1.0f;  // root: identity
    } else if (b <= 48) {
        // Layer-1 GEMM1: n1[(u*6+d)*H1 + o] = sum_i x[u,i] * Wd[i*H1+o]
        const int bb = b - 1;
        const int d = bb >> 3;
        const int chunk = bb & 7;
        __shared__ float xs[NN * D0];
        for (int i = tid; i < NN * D0; i += 256) xs[i] = x[i];
        __syncthreads();
        const int o = chunk * 256 + tid;
        if (o < H1) {
            const float* Wd = (d < 4) ? (We1 + d * (D0 * H1))
                                      : ((d == 4) ? be1 : root1);
            float w[D0];
            #pragma unroll
            for (int i = 0; i < D0; ++i) w[i] = Wd[i * H1 + o];
            float* n1 = ws + OFF_N1;
            for (int u = 0; u < NN; ++u) {
                float acc = 0.f;
                #pragma unroll
                for (int i = 0; i < D0; ++i) acc += xs[u * D0 + i] * w[i];
                n1[(u * 6 + d) * H1 + o] = acc;
            }
        }
    } else {
        // Bias fills + n3 zero. 204800 elements total.
        const int stride = (gridDim.x - 49) * 256;
        for (int i = (b - 49) * 256 + tid; i < 204800; i += stride) {
            if (i < 128000)        ws[OFF_PRE1 + i] = b1[i % H1];
            else if (i < 160000) { int j = i - 128000; ws[OFF_PRE2 + j] = b2[j % H2]; }
            else if (i < 166400) { int j = i - 160000; ws[OFF_PRE3 + j] = b3[j % H3]; }
            else                   ws[OFF_N3 + (i - 166400)] = 0.f;
        }
    }
}

// ---------------------------------------------------------------------------
// GEMM1 (layers 2,3): C[64 x 6M] = relu(pre)[64 x K] @ Wcat[K x 6M]
// Wcat column j=(d*M+o) maps to We[d]/be/root columns. 64x64 tiles, K-split.
// ---------------------------------------------------------------------------
__global__ __launch_bounds__(256) void k_gemm1(
    const float* __restrict__ pre,
    const float* __restrict__ We, const float* __restrict__ be,
    const float* __restrict__ root,
    float* __restrict__ outBase,
    int K, int M, int jTiles, int spanLen, int nIter,
    long long sStride, int useAtomic)
{
    const int Mj = 6 * M;
    const int s  = blockIdx.x / jTiles;
    const int jt = blockIdx.x % jTiles;
    const int k0 = s * spanLen;
    const int tid = threadIdx.x;
    const int tx = tid & 15, ty = tid >> 4;
    const int j0 = jt * 64;
    constexpr int KC = 25;

    __shared__ float As[64 * 27];                 // [r][kk], padded
    __shared__ __align__(16) float Bs[KC * 64];   // [kk][c]
    __shared__ const float* cp[64];

    if (tid < 64) {
        int j = j0 + tid;
        int jc = j < Mj ? j : Mj - 1;
        int d = jc / M, o = jc - d * M;
        const float* base = (d < 4) ? (We + (size_t)d * K * M)
                                    : ((d == 4) ? be : root);
        cp[tid] = base + o;
    }

    float acc[4][4] = {};
    for (int it = 0; it < nIter; ++it) {
        const int kb = k0 + it * KC;
        __syncthreads();
        for (int idx = tid; idx < 64 * KC; idx += 256) {
            int r = idx / KC, kk = idx - r * KC;
            float v = pre[r * K + kb + kk];
            As[r * 27 + kk] = v > 0.f ? v : 0.f;
        }
        for (int idx = tid; idx < KC * 64; idx += 256) {
            int kk = idx >> 6, c = idx & 63;
            Bs[kk * 64 + c] = cp[c][(size_t)(kb + kk) * M];
        }
        __syncthreads();
        #pragma unroll
        for (int kk = 0; kk < KC; ++kk) {
            float a0 = As[(ty * 4 + 0) * 27 + kk];
            float a1 = As[(ty * 4 + 1) * 27 + kk];
            float a2 = As[(ty * 4 + 2) * 27 + kk];
            float a3 = As[(ty * 4 + 3) * 27 + kk];
            const float4 bv = *(const float4*)&Bs[kk * 64 + tx * 4];
            acc[0][0] += a0 * bv.x; acc[0][1] += a0 * bv.y;
            acc[0][2] += a0 * bv.z; acc[0][3] += a0 * bv.w;
            acc[1][0] += a1 * bv.x; acc[1][1] += a1 * bv.y;
            acc[1][2] += a1 * bv.z; acc[1][3] += a1 * bv.w;
            acc[2][0] += a2 * bv.x; acc[2][1] += a2 * bv.y;
            acc[2][2] += a2 * bv.z; acc[2][3] += a2 * bv.w;
            acc[3][0] += a3 * bv.x; acc[3][1] += a3 * bv.y;
            acc[3][2] += a3 * bv.z; acc[3][3] += a3 * bv.w;
        }
    }
    float* outP = outBase + (useAtomic ? 0 : (long long)s * sStride);
    #pragma unroll
    for (int i = 0; i < 4; ++i) {
        int u = ty * 4 + i;
        #pragma unroll
        for (int jj = 0; jj < 4; ++jj) {
            int j = j0 + tx * 4 + jj;
            if (j < Mj) {
                if (useAtomic) atomicAdd(&outP[u * Mj + j], acc[i][jj]);
                else           outP[u * Mj + j] = acc[i][jj];
            }
        }
    }
}

// ---------------------------------------------------------------------------
// GEMM2: pre[64 x M] += A-hat[64 x 384] @ (sum_s B_s[384 x M]); K-split+atomic
// ---------------------------------------------------------------------------
__global__ __launch_bounds__(256) void k_gemm2(
    const float* __restrict__ A, const float* __restrict__ B,
    float* __restrict__ out,
    int M, int jTiles, int spanLen, int nIter, int nS, long long sStride)
{
    const int s  = blockIdx.x / jTiles;
    const int jt = blockIdx.x % jTiles;
    const int k0 = s * spanLen;
    const int tid = threadIdx.x;
    const int tx = tid & 15, ty = tid >> 4;
    const int j0 = jt * 64;
    constexpr int KC = 16;

    __shared__ float As[64 * 17];
    __shared__ __align__(16) float Bs[KC * 64];

    float acc[4][4] = {};
    for (int it = 0; it < nIter; ++it) {
        const int kb = k0 + it * KC;
        __syncthreads();
        for (int idx = tid; idx < 64 * KC; idx += 256) {
            int r = idx >> 4, kk = idx & 15;
            As[r * 17 + kk] = A[r * KDIM + kb + kk];
        }
        for (int idx = tid; idx < KC * 64; idx += 256) {
            int kk = idx >> 6, c = idx & 63;
            int j = j0 + c; int jc = j < M ? j : M - 1;
            float v = 0.f;
            for (int ss = 0; ss < nS; ++ss)
                v += B[(long long)ss * sStride + (kb + kk) * M + jc];
            Bs[kk * 64 + c] = v;
        }
        __syncthreads();
        #pragma unroll
        for (int kk = 0; kk < KC; ++kk) {
            float a0 = As[(ty * 4 + 0) * 17 + kk];
            float a1 = As[(ty * 4 + 1) * 17 + kk];
            float a2 = As[(ty * 4 + 2) * 17 + kk];
            float a3 = As[(ty * 4 + 3) * 17 + kk];
            const float4 bv = *(const float4*)&Bs[kk * 64 + tx * 4];
            acc[0][0] += a0 * bv.x; acc[0][1] += a0 * bv.y;
            acc[0][2] += a0 * bv.z; acc[0][3] += a0 * bv.w;
            acc[1][0] += a1 * bv.x; acc[1][1] += a1 * bv.y;
            acc[1][2] += a1 * bv.z; acc[1][3] += a1 * bv.w;
            acc[2][0] += a2 * bv.x; acc[2][1] += a2 * bv.y;
            acc[2][2] += a2 * bv.z; acc[2][3] += a2 * bv.w;
            acc[3][0] += a3 * bv.x; acc[3][1] += a3 * bv.y;
            acc[3][2] += a3 * bv.z; acc[3][3] += a3 * bv.w;
        }
    }
    #pragma unroll
    for (int i = 0; i < 4; ++i) {
        int u = ty * 4 + i;
        #pragma unroll
        for (int jj = 0; jj < 4; ++jj) {
            int j = j0 + tx * 4 + jj;
            if (j < M) atomicAdd(&out[u * M + j], acc[i][jj]);
        }
    }
}

// ---------------------------------------------------------------------------
// Head: segment-sum readout + 4-layer MLP, single block (tiny).
// ---------------------------------------------------------------------------
__global__ __launch_bounds__(1024) void k_head(
    const float* __restrict__ pre3, const int* __restrict__ batch,
    const float* __restrict__ W1, const float* __restrict__ c1,
    const float* __restrict__ W2, const float* __restrict__ c2,
    const float* __restrict__ W3, const float* __restrict__ c3,
    const float* __restrict__ W4, const float* __restrict__ c4,
    float* __restrict__ out)
{
    __shared__ int   bsh[NN];
    __shared__ float g[GG * H3];
    __shared__ float f1[GG * FF1];
    __shared__ float f2[GG * FF2];
    __shared__ float f3[GG * FF3];
    const int tid = threadIdx.x;
    if (tid < NN) bsh[tid] = batch[tid];
    __syncthreads();
    if (tid < GG * H3) {
        int gi = tid / H3, o = tid % H3;
        float acc = 0.f;
        for (int v = 0; v < NN; ++v) {
            float h = pre3[v * H3 + o];
            h = h > 0.f ? h : 0.f;
            acc += (bsh[v] == gi) ? h : 0.f;
        }
        g[tid] = acc;
    }
    __syncthreads();
    for (int idx = tid; idx < GG * FF1; idx += 1024) {
        int gi = idx / FF1, o = idx - gi * FF1;
        float acc = c1[o];
        for (int k = 0; k < H3; ++k) acc += g[gi * H3 + k] * W1[k * FF1 + o];
        f1[idx] = acc > 0.f ? acc : 0.f;
    }
    __syncthreads();
    if (tid < GG * FF2) {
        int gi = tid / FF2, o = tid - gi * FF2;
        float acc = c2[o];
        for (int k = 0; k < FF1; ++k) acc += f1[gi * FF1 + k] * W2[k * FF2 + o];
        f2[tid] = acc > 0.f ? acc : 0.f;
    }
    __syncthreads();
    if (tid < GG * FF3) {
        int gi = tid / FF3, o = tid - gi * FF3;
        float acc = c3[o];
        for (int k = 0; k < FF2; ++k) acc += f2[gi * FF2 + k] * W3[k * FF3 + o];
        f3[tid] = acc > 0.f ? acc : 0.f;
    }
    __syncthreads();
    if (tid < GG) {
        float acc = c4[0];
        for (int k = 0; k < FF3; ++k) acc += f3[tid * FF3 + k] * W4[k];
        out[tid] = acc;
    }
}

extern "C" void kernel_launch(void* const* d_in, const int* in_sizes, int n_in,
                              void* d_out, int out_size, void* d_ws, size_t ws_size,
                              hipStream_t stream) {
    const float* x          = (const float*)d_in[0];
    const int*   edge_index = (const int*)  d_in[1];
    const float* edge_attr  = (const float*)d_in[2];
    const int*   batch      = (const int*)  d_in[3];
    const float* We1 = (const float*)d_in[4];
    const float* be1 = (const float*)d_in[5];
    const float* root1 = (const float*)d_in[6];
    const float* b1  = (const float*)d_in[7];
    const float* We2 = (const float*)d_in[8];
    const float* be2 = (const float*)d_in[9];
    const float* root2 = (const float*)d_in[10];
    const float* b2  = (const float*)d_in[11];
    const float* We3 = (const float*)d_in[12];
    const float* be3 = (const float*)d_in[13];
    const float* root3 = (const float*)d_in[14];
    const float* b3  = (const float*)d_in[15];
    const float* W1 = (const float*)d_in[16];
    const float* c1 = (const float*)d_in[17];
    const float* W2 = (const float*)d_in[18];
    const float* c2 = (const float*)d_in[19];
    const float* W3 = (const float*)d_in[20];
    const float* c3 = (const float*)d_in[21];
    const float* W4 = (const float*)d_in[22];
    const float* c4 = (const float*)d_in[23];
    float* ws  = (float*)d_ws;
    float* out = (float*)d_out;

    // K0: A-hat + bias fills + n3 zero + layer1 GEMM1 (n1)
    k_init<<<249, 256, 0, stream>>>(x, edge_index, edge_attr,
                                    We1, be1, root1, b1, b2, b3, ws);
    // L1 GEMM2: pre1 += A @ n1   [64x2000, K=384, split 4]
    k_gemm2<<<128, 256, 0, stream>>>(ws + OFF_A, ws + OFF_N1, ws + OFF_PRE1,
                                     H1, 32, 96, 6, 1, 0);
    // L2 GEMM1: n2 partials = relu(pre1) @ Wcat2   [64x3000, K=2000, split 8]
    k_gemm1<<<376, 256, 0, stream>>>(ws + OFF_PRE1, We2, be2, root2,
                                     ws + OFF_N2P, H1, H2, 47, 250, 10,
                                     (long long)KDIM * H2, 0);
    // L2 GEMM2: pre2 += A @ sum_s(n2_s)   [64x500, K=384, split 4]
    k_gemm2<<<32, 256, 0, stream>>>(ws + OFF_A, ws + OFF_N2P, ws + OFF_PRE2,
                                    H2, 8, 96, 6, 8, (long long)KDIM * H2);
    // L3 GEMM1: n3 += relu(pre2) @ Wcat3   [64x600, K=500, split 4, atomic]
    k_gemm1<<<40, 256, 0, stream>>>(ws + OFF_PRE2, We3, be3, root3,
                                    ws + OFF_N3, H2, H3, 10, 125, 5, 0LL, 1);
    // L3 GEMM2: pre3 += A @ n3   [64x100, K=384, split 8]
    k_gemm2<<<16, 256, 0, stream>>>(ws + OFF_A, ws + OFF_N3, ws + OFF_PRE3,
                                    H3, 2, 48, 3, 1, 0);
    // Head
    k_head<<<1, 1024, 0, stream>>>(ws + OFF_PRE3, batch,
                                   W1, c1, W2, c2, W3, c3, W4, c4, out);
}

// Round 2
// 239.603 us; speedup vs baseline: 1.5151x; 1.5151x over previous
//
#include <hip/hip_runtime.h>

// Problem dims
#define NN 64
#define EE 128
#define GG 4
#define D0 9
#define EDIM 4
#define H1 2000
#define H2 500
#define H3 100
#define FF1 1000
#define FF2 100
#define FF3 50
#define KDIM 384   // 64 nodes * 6 channels

// Workspace layout (floats)
#define OFF_A    0        // 64*384   = 24576  A-hat
#define OFF_Y    24576    // 64*54    = 3456   folded layer-1 input
#define OFF_PRE1 28032    // 64*2000  = 128000
#define OFF_PRE2 156032   // 64*500   = 32000
#define OFF_PRE3 188032   // 64*100   = 6400
#define OFF_N2   194432   // 384*500  = 192000
#define OFF_N3   386432   // 384*100  = 38400
#define OFF_F1   424832   // 4*1000   = 4000
#define OFF_F2   428832   // 4*100    = 400
// total 429232 floats = 1.72 MB

#define FILLN 269200

// ---------------------------------------------------------------------------
// K0: block0 = A-hat, block1 = Y, blocks 2.. = bias preloads + zero fills
// ---------------------------------------------------------------------------
__global__ __launch_bounds__(256) void k_init(
    const float* __restrict__ x, const int* __restrict__ edge_index,
    const float* __restrict__ edge_attr,
    const float* __restrict__ b2, const float* __restrict__ b3,
    const float* __restrict__ c2, float* __restrict__ ws)
{
    const int b = blockIdx.x, tid = threadIdx.x;
    if (b == 0) {
        float* A = ws + OFF_A;
        for (int i = tid; i < NN * KDIM; i += 256) A[i] = 0.f;
        __syncthreads();
        if (tid < EE) {
            int s = edge_index[tid];
            int t = edge_index[EE + tid];
            float* row = A + t * KDIM + s * 6;
            #pragma unroll
            for (int d = 0; d < 4; ++d) atomicAdd(row + d, edge_attr[tid * 4 + d]);
            atomicAdd(row + 4, 1.0f);
        }
        if (tid < NN) A[tid * KDIM + tid * 6 + 5] = 1.0f;
    } else if (b == 1) {
        // Y[u, d*9+i]: d<4 edge-weighted scatter of x[src], d=4 edge-count
        // scatter, d=5 identity (x itself)
        __shared__ float Ys[NN * 54];
        for (int i = tid; i < NN * 54; i += 256) Ys[i] = 0.f;
        __syncthreads();
        if (tid < EE) {
            int s = edge_index[tid];
            int t = edge_index[EE + tid];
            float ea[4];
            #pragma unroll
            for (int d = 0; d < 4; ++d) ea[d] = edge_attr[tid * 4 + d];
            #pragma unroll
            for (int i = 0; i < D0; ++i) {
                float xv = x[s * D0 + i];
                #pragma unroll
                for (int d = 0; d < 4; ++d)
                    atomicAdd(&Ys[t * 54 + d * 9 + i], ea[d] * xv);
                atomicAdd(&Ys[t * 54 + 36 + i], xv);
            }
        }
        if (tid < NN) {
            #pragma unroll
            for (int i = 0; i < D0; ++i) Ys[tid * 54 + 45 + i] = x[tid * D0 + i];
        }
        __syncthreads();
        for (int i = tid; i < NN * 54; i += 256) ws[OFF_Y + i] = Ys[i];
    } else {
        const int stride = (gridDim.x - 2) * 256;
        for (int i = (b - 2) * 256 + tid; i < FILLN; i += stride) {
            if (i < 32000)         ws[OFF_PRE2 + i] = b2[i % H2];
            else if (i < 38400)  { int j = i - 32000;  ws[OFF_PRE3 + j] = b3[j % H3]; }
            else if (i < 230400)   ws[OFF_N2 + (i - 38400)] = 0.f;
            else if (i < 268800)   ws[OFF_N3 + (i - 230400)] = 0.f;
            else                 { int j = i - 268800; ws[OFF_F2 + j] = c2[j % FF2]; }
        }
    }
}

// ---------------------------------------------------------------------------
// K1: pre1[64x2000] = b1 + Y[64x54] @ Wall1[54x2000]
// ---------------------------------------------------------------------------
__global__ __launch_bounds__(256) void k_lin1(
    const float* __restrict__ Yw,
    const float* __restrict__ We1, const float* __restrict__ be1,
    const float* __restrict__ root1, const float* __restrict__ b1,
    float* __restrict__ pre1)
{
    const int tid = threadIdx.x;
    const int tx = tid & 15, ty = tid >> 4;
    const int o0 = blockIdx.x * 64;
    const int w = min(64, H1 - o0);

    __shared__ float Ys[64 * 56];
    __shared__ __align__(16) float Bs[54 * 64];

    for (int i = tid; i < 64 * 54; i += 256) {
        int u = i / 54, r = i - u * 54;
        Ys[u * 56 + r] = Yw[i];
    }
    for (int i = tid; i < 54 * 64; i += 256) {
        int r = i >> 6, c = i & 63;
        int d = r / 9, ii = r - d * 9;
        const float* rowp = ((d < 4) ? (We1 + d * (D0 * H1))
                                     : ((d == 4) ? be1 : root1)) + ii * H1;
        Bs[r * 64 + c] = (c < w) ? rowp[o0 + c] : 0.f;
    }
    __syncthreads();

    float acc[4][4] = {};
    #pragma unroll 6
    for (int r = 0; r < 54; ++r) {
        float a0 = Ys[(ty * 4 + 0) * 56 + r];
        float a1 = Ys[(ty * 4 + 1) * 56 + r];
        float a2 = Ys[(ty * 4 + 2) * 56 + r];
        float a3 = Ys[(ty * 4 + 3) * 56 + r];
        const float4 bv = *(const float4*)&Bs[r * 64 + tx * 4];
        acc[0][0] += a0 * bv.x; acc[0][1] += a0 * bv.y; acc[0][2] += a0 * bv.z; acc[0][3] += a0 * bv.w;
        acc[1][0] += a1 * bv.x; acc[1][1] += a1 * bv.y; acc[1][2] += a1 * bv.z; acc[1][3] += a1 * bv.w;
        acc[2][0] += a2 * bv.x; acc[2][1] += a2 * bv.y; acc[2][2] += a2 * bv.z; acc[2][3] += a2 * bv.w;
        acc[3][0] += a3 * bv.x; acc[3][1] += a3 * bv.y; acc[3][2] += a3 * bv.z; acc[3][3] += a3 * bv.w;
    }
    #pragma unroll
    for (int i = 0; i < 4; ++i) {
        int u = ty * 4 + i;
        #pragma unroll
        for (int jj = 0; jj < 4; ++jj) {
            int j = o0 + tx * 4 + jj;
            if (j < H1) pre1[u * H1 + j] = b1[j] + acc[i][jj];
        }
    }
}

// ---------------------------------------------------------------------------
// k_msg (GEMM1): n[(u*6+d)*M+o] += relu(pre)[64xK] @ Wsec_d[KxM]
// grid = (d*OT + ot)*S + s ; span = ITERS*KC ; float4 loads both sides.
// ---------------------------------------------------------------------------
template<int KC, int ITERS>
__global__ __launch_bounds__(256) void k_msg(
    const float* __restrict__ pre, int K,
    const float* __restrict__ We, const float* __restrict__ be,
    const float* __restrict__ root, long long secSize,
    int M, int OT, int S, float* __restrict__ n)
{
    constexpr int APAD = KC + 4;
    const int b  = blockIdx.x;
    const int s  = b % S;
    const int t2 = b / S;
    const int ot = t2 % OT;
    const int d  = t2 / OT;
    const int tid = threadIdx.x;
    const int tx = tid & 15, ty = tid >> 4;
    const int o0 = ot * 64;
    const int w  = min(64, M - o0);
    const int w4 = w >> 2;

    const float* Bbase = (d < 4) ? (We + (long long)d * secSize)
                                 : ((d == 4) ? be : root);

    __shared__ __align__(16) float As[64 * APAD];
    __shared__ __align__(16) float Bs[KC * 64];

    float acc[4][4] = {};
    for (int it = 0; it < ITERS; ++it) {
        const int kb = s * (KC * ITERS) + it * KC;
        __syncthreads();
        for (int idx = tid; idx < 64 * (KC / 4); idx += 256) {
            int r = idx / (KC / 4), c4 = idx % (KC / 4);
            float4 v = *(const float4*)(pre + r * K + kb + c4 * 4);
            v.x = v.x > 0.f ? v.x : 0.f; v.y = v.y > 0.f ? v.y : 0.f;
            v.z = v.z > 0.f ? v.z : 0.f; v.w = v.w > 0.f ? v.w : 0.f;
            *(float4*)&As[r * APAD + c4 * 4] = v;
        }
        for (int idx = tid; idx < KC * 16; idx += 256) {
            int r = idx >> 4, c4 = idx & 15;
            if (c4 < w4) {
                float4 v = *(const float4*)(Bbase + (long long)(kb + r) * M + o0 + c4 * 4);
                *(float4*)&Bs[r * 64 + c4 * 4] = v;
            }
        }
        __syncthreads();
        #pragma unroll 8
        for (int kk = 0; kk < KC; ++kk) {
            float a0 = As[(ty * 4 + 0) * APAD + kk];
            float a1 = As[(ty * 4 + 1) * APAD + kk];
            float a2 = As[(ty * 4 + 2) * APAD + kk];
            float a3 = As[(ty * 4 + 3) * APAD + kk];
            const float4 bv = *(const float4*)&Bs[kk * 64 + tx * 4];
            acc[0][0] += a0 * bv.x; acc[0][1] += a0 * bv.y; acc[0][2] += a0 * bv.z; acc[0][3] += a0 * bv.w;
            acc[1][0] += a1 * bv.x; acc[1][1] += a1 * bv.y; acc[1][2] += a1 * bv.z; acc[1][3] += a1 * bv.w;
            acc[2][0] += a2 * bv.x; acc[2][1] += a2 * bv.y; acc[2][2] += a2 * bv.z; acc[2][3] += a2 * bv.w;
            acc[3][0] += a3 * bv.x; acc[3][1] += a3 * bv.y; acc[3][2] += a3 * bv.z; acc[3][3] += a3 * bv.w;
        }
    }
    #pragma unroll
    for (int i = 0; i < 4; ++i) {
        int u = ty * 4 + i;
        #pragma unroll
        for (int jj = 0; jj < 4; ++jj) {
            int j = o0 + tx * 4 + jj;
            if (j < M) atomicAdd(&n[(u * 6 + d) * M + j], acc[i][jj]);
        }
    }
}

// ---------------------------------------------------------------------------
// k_agg (GEMM2): pre[64xM] += A-hat[64x384] @ n[384xM]; K=384 = 8 spans x 48
// grid = ot*8 + s
// ---------------------------------------------------------------------------
__global__ __launch_bounds__(256) void k_agg(
    const float* __restrict__ A, const float* __restrict__ B,
    int M, float* __restrict__ out)
{
    constexpr int KC = 48, APAD = 52;
    const int s  = blockIdx.x & 7;
    const int ot = blockIdx.x >> 3;
    const int tid = threadIdx.x;
    const int tx = tid & 15, ty = tid >> 4;
    const int o0 = ot * 64;
    const int w  = min(64, M - o0);
    const int w4 = w >> 2;
    const int kb = s * KC;

    __shared__ __align__(16) float As[64 * APAD];
    __shared__ __align__(16) float Bs[KC * 64];

    for (int idx = tid; idx < 64 * (KC / 4); idx += 256) {
        int r = idx / (KC / 4), c4 = idx % (KC / 4);
        *(float4*)&As[r * APAD + c4 * 4] =
            *(const float4*)(A + r * KDIM + kb + c4 * 4);
    }
    for (int idx = tid; idx < KC * 16; idx += 256) {
        int r = idx >> 4, c4 = idx & 15;
        if (c4 < w4)
            *(float4*)&Bs[r * 64 + c4 * 4] =
                *(const float4*)(B + (kb + r) * M + o0 + c4 * 4);
    }
    __syncthreads();

    float acc[4][4] = {};
    #pragma unroll 8
    for (int kk = 0; kk < KC; ++kk) {
        float a0 = As[(ty * 4 + 0) * APAD + kk];
        float a1 = As[(ty * 4 + 1) * APAD + kk];
        float a2 = As[(ty * 4 + 2) * APAD + kk];
        float a3 = As[(ty * 4 + 3) * APAD + kk];
        const float4 bv = *(const float4*)&Bs[kk * 64 + tx * 4];
        acc[0][0] += a0 * bv.x; acc[0][1] += a0 * bv.y; acc[0][2] += a0 * bv.z; acc[0][3] += a0 * bv.w;
        acc[1][0] += a1 * bv.x; acc[1][1] += a1 * bv.y; acc[1][2] += a1 * bv.z; acc[1][3] += a1 * bv.w;
        acc[2][0] += a2 * bv.x; acc[2][1] += a2 * bv.y; acc[2][2] += a2 * bv.z; acc[2][3] += a2 * bv.w;
        acc[3][0] += a3 * bv.x; acc[3][1] += a3 * bv.y; acc[3][2] += a3 * bv.z; acc[3][3] += a3 * bv.w;
    }
    #pragma unroll
    for (int i = 0; i < 4; ++i) {
        int u = ty * 4 + i;
        #pragma unroll
        for (int jj = 0; jj < 4; ++jj) {
            int j = o0 + tx * 4 + jj;
            if (j < M) atomicAdd(&out[u * M + j], acc[i][jj]);
        }
    }
}

// ---------------------------------------------------------------------------
// K6: per (gi, o-tile) block: g[gi] = segment-sum relu(pre3), then
//     f1[gi, o-tile] = relu(c1 + g @ W1)
// ---------------------------------------------------------------------------
__global__ __launch_bounds__(256) void k_head1(
    const float* __restrict__ pre3, const int* __restrict__ batch,
    const float* __restrict__ W1, const float* __restrict__ c1,
    float* __restrict__ f1)
{
    const int gi = blockIdx.x >> 4;
    const int jt = blockIdx.x & 15;
    const int o0 = jt * 64;
    const int tid = threadIdx.x;
    __shared__ int   bsh[NN];
    __shared__ float gs[H3];
    __shared__ float red[4 * 64];

    if (tid < NN) bsh[tid] = batch[tid];
    __syncthreads();
    for (int d = tid; d < H3; d += 256) {
        float acc = 0.f;
        #pragma unroll
        for (int v = 0; v < NN; ++v) {
            float h = pre3[v * H3 + d];
            h = h > 0.f ? h : 0.f;
            acc += (bsh[v] == gi) ? h : 0.f;
        }
        gs[d] = acc;
    }
    __syncthreads();
    const int jj = tid & 63, kq = tid >> 6;
    const int oc = min(o0 + jj, FF1 - 1);
    float p = 0.f;
    #pragma unroll
    for (int k = kq * 25; k < kq * 25 + 25; ++k)
        p += gs[k] * W1[k * FF1 + oc];
    red[kq * 64 + jj] = p;
    __syncthreads();
    if (tid < 64) {
        int o = o0 + tid;
        if (o < FF1) {
            float v = c1[o] + red[tid] + red[64 + tid] + red[128 + tid] + red[192 + tid];
            f1[gi * FF1 + o] = v > 0.f ? v : 0.f;
        }
    }
}

// ---------------------------------------------------------------------------
// K7: f2 += f1 @ W2  (K=1000 split over 16 blocks, atomic; c2 preloaded)
// ---------------------------------------------------------------------------
__global__ __launch_bounds__(256) void k_head2(
    const float* __restrict__ f1, const float* __restrict__ W2,
    float* __restrict__ f2)
{
    const int s = blockIdx.x;
    const int k0 = s * 63;
    const int kn = min(63, FF1 - k0);
    const int tid = threadIdx.x;
    __shared__ float f1s[4 * 63];
    for (int i = tid; i < 4 * kn; i += 256) {
        int gi = i / kn, kk = i - gi * kn;
        f1s[gi * 63 + kk] = f1[gi * FF1 + k0 + kk];
    }
    __syncthreads();
    for (int idx = tid; idx < GG * FF2; idx += 256) {
        int gi = idx / FF2, o = idx - gi * FF2;
        float acc = 0.f;
        for (int kk = 0; kk < kn; ++kk)
            acc += f1s[gi * 63 + kk] * W2[(k0 + kk) * FF2 + o];
        atomicAdd(&f2[idx], acc);
    }
}

// ---------------------------------------------------------------------------
// K8: f3 = relu(relu(f2) @ W3 + c3); out = f3 @ W4 + c4   (single tiny block)
// ---------------------------------------------------------------------------
__global__ __launch_bounds__(256) void k_head3(
    const float* __restrict__ f2, const float* __restrict__ W3,
    const float* __restrict__ c3, const float* __restrict__ W4,
    const float* __restrict__ c4, float* __restrict__ out)
{
    const int tid = threadIdx.x;
    __shared__ float f2s[GG * FF2];
    __shared__ float f3s[GG * FF3];
    for (int i = tid; i < GG * FF2; i += 256) {
        float v = f2[i];
        f2s[i] = v > 0.f ? v : 0.f;
    }
    __syncthreads();
    if (tid < GG * FF3) {
        int gi = tid / FF3, o = tid - gi * FF3;
        float acc = c3[o];
        for (int k = 0; k < FF2; ++k)
            acc += f2s[gi * FF2 + k] * W3[k * FF3 + o];
        f3s[tid] = acc > 0.f ? acc : 0.f;
    }
    __syncthreads();
    if (tid < GG) {
        float acc = c4[0];
        #pragma unroll
        for (int k = 0; k < FF3; ++k) acc += f3s[tid * FF3 + k] * W4[k];
        out[tid] = acc;
    }
}

extern "C" void kernel_launch(void* const* d_in, const int* in_sizes, int n_in,
                              void* d_out, int out_size, void* d_ws, size_t ws_size,
                              hipStream_t stream) {
    const float* x          = (const float*)d_in[0];
    const int*   edge_index = (const int*)  d_in[1];
    const float* edge_attr  = (const float*)d_in[2];
    const int*   batch      = (const int*)  d_in[3];
    const float* We1 = (const float*)d_in[4];
    const float* be1 = (const float*)d_in[5];
    const float* root1 = (const float*)d_in[6];
    const float* b1  = (const float*)d_in[7];
    const float* We2 = (const float*)d_in[8];
    const float* be2 = (const float*)d_in[9];
    const float* root2 = (const float*)d_in[10];
    const float* b2  = (const float*)d_in[11];
    const float* We3 = (const float*)d_in[12];
    const float* be3 = (const float*)d_in[13];
    const float* root3 = (const float*)d_in[14];
    const float* b3  = (const float*)d_in[15];
    const float* W1 = (const float*)d_in[16];
    const float* c1 = (const float*)d_in[17];
    const float* W2 = (const float*)d_in[18];
    const float* c2 = (const float*)d_in[19];
    const float* W3 = (const float*)d_in[20];
    const float* c3 = (const float*)d_in[21];
    const float* W4 = (const float*)d_in[22];
    const float* c4 = (const float*)d_in[23];
    float* ws  = (float*)d_ws;
    float* out = (float*)d_out;

    // K0: A-hat + Y + bias preloads + zero fills
    k_init<<<66, 256, 0, stream>>>(x, edge_index, edge_attr, b2, b3, c2, ws);
    // K1: pre1 = b1 + Y @ Wall1   [64x2000, K=54]
    k_lin1<<<32, 256, 0, stream>>>(ws + OFF_Y, We1, be1, root1, b1, ws + OFF_PRE1);
    // K2: n2 += relu(pre1) @ Wcat2   [K=2000, M=500] grid 6*8*10
    k_msg<40, 5><<<480, 256, 0, stream>>>(ws + OFF_PRE1, H1, We2, be2, root2,
                                          (long long)H1 * H2, H2, 8, 10,
                                          ws + OFF_N2);
    // K3: pre2 += A-hat @ n2   [M=500] grid 8*8
    k_agg<<<64, 256, 0, stream>>>(ws + OFF_A, ws + OFF_N2, H2, ws + OFF_PRE2);
    // K4: n3 += relu(pre2) @ Wcat3   [K=500, M=100] grid 6*2*5
    k_msg<20, 5><<<60, 256, 0, stream>>>(ws + OFF_PRE2, H2, We3, be3, root3,
                                         (long long)H2 * H3, H3, 2, 5,
                                         ws + OFF_N3);
    // K5: pre3 += A-hat @ n3   [M=100] grid 2*8
    k_agg<<<16, 256, 0, stream>>>(ws + OFF_A, ws + OFF_N3, H3, ws + OFF_PRE3);
    // K6: g + f1
    k_head1<<<64, 256, 0, stream>>>(ws + OFF_PRE3, batch, W1, c1, ws + OFF_F1);
    // K7: f2
    k_head2<<<16, 256, 0, stream>>>(ws + OFF_F1, W2, ws + OFF_F2);
    // K8: f3 + out
    k_head3<<<1, 256, 0, stream>>>(ws + OFF_F2, W3, c3, W4, c4, out);
}